// Round 8
// baseline (1286.378 us; speedup 1.0000x reference)
//
#include <hip/hip_runtime.h>
#include <math.h>

#define BB 16
#define NN 512
#define KNN 8
#define SEQ 12
#define TQ 8            // knn: threads per query
#define QB 32           // knn: queries per block (TQ*QB = 256 threads)
#define PB 16           // cells: points per block

typedef __attribute__((ext_vector_type(8))) short bf8_t;   // 8 bf16 (4 VGPRs)
typedef __attribute__((ext_vector_type(4))) float f4_t;    // MFMA acc

__device__ __forceinline__ ushort f2b(float x) {           // fp32 -> bf16 RNE
    uint u = __float_as_uint(x);
    return (ushort)((u + 0x7fffu + ((u >> 16) & 1u)) >> 16);
}
__device__ __forceinline__ float b2f(ushort h) {
    return __uint_as_float((uint)h << 16);
}

// ---------------------------------------------------------------------------
// KNN (unchanged — verified correct, conflict-free layout).
// ---------------------------------------------------------------------------
__global__ __launch_bounds__(256) void knn_kernel(
        const float* __restrict__ xq, int xq_bs,
        const float* __restrict__ xs, int xs_bs,
        int* __restrict__ idx1, int* __restrict__ idx2, int* __restrict__ idx3,
        float r2a, float r2b, float r2c, int warm) {
    __shared__ float s[NN * 3 + NN / 64];
    __shared__ float cd[QB][TQ][KNN + 1];
    __shared__ int   ci[QB][TQ][KNN + 1];
    int b = blockIdx.y;
    const float* xqp; const float* xsp; long iofs;
    if (warm) {
        int z = blockIdx.z;
        int qz = z < 5 ? z : 5;
        int sz = z - 1 < 0 ? 0 : z - 1;
        xqp = xq + (long)qz * NN * 3;
        xsp = xq + (long)sz * NN * 3;
        xs_bs = xq_bs;
        iofs = (long)z * BB * NN * KNN;
    } else {
        xqp = xq; xsp = xs; iofs = 0;
    }

    for (int j = threadIdx.x; j < NN; j += 256) {
        const float* p = xsp + (long)b * xs_bs + j * 3;
        int o = 3 * j + (j >> 6);
        s[o + 0] = p[0]; s[o + 1] = p[1]; s[o + 2] = p[2];
    }
    __syncthreads();

    int qi  = threadIdx.x / TQ;
    int sub = threadIdx.x % TQ;
    int n = blockIdx.x * QB + qi;
    const float* q = xqp + (long)b * xq_bs + n * 3;
    float qx = q[0], qy = q[1], qz2 = q[2];

    float bd[KNN];
    int   bi[KNN];
#pragma unroll
    for (int k = 0; k < KNN; ++k) { bd[k] = 1e30f; bi[k] = 0; }

    int j0 = sub * (NN / TQ);
    int sbase = 3 * j0 + sub;
#pragma unroll 4
    for (int jj = 0; jj < NN / TQ; ++jj) {
        float dx = s[sbase + 3 * jj + 0] - qx;
        float dy = s[sbase + 3 * jj + 1] - qy;
        float dz = s[sbase + 3 * jj + 2] - qz2;
        float d2 = fmaf(dx, dx, fmaf(dy, dy, dz * dz));
        if (d2 < bd[KNN - 1]) {
            bd[KNN - 1] = d2; bi[KNN - 1] = j0 + jj;
#pragma unroll
            for (int k = KNN - 1; k >= 1; --k) {
                if (bd[k] < bd[k - 1]) {
                    float td = bd[k]; bd[k] = bd[k - 1]; bd[k - 1] = td;
                    int   ti = bi[k]; bi[k] = bi[k - 1]; bi[k - 1] = ti;
                }
            }
        }
    }

#pragma unroll
    for (int k = 0; k < KNN; ++k) { cd[qi][sub][k] = bd[k]; ci[qi][sub][k] = bi[k]; }
    cd[qi][sub][KNN] = 1e30f; ci[qi][sub][KNN] = 0x7fffffff;
    __syncthreads();

    for (int stride = TQ / 2; stride >= 1; stride >>= 1) {
        if (sub < stride) {
            float rd[KNN]; int ri[KNN];
            int ia = 0, ib = 0;
#pragma unroll
            for (int k = 0; k < KNN; ++k) {
                float da = cd[qi][sub][ia], db = cd[qi][sub + stride][ib];
                int   ja = ci[qi][sub][ia], jb = ci[qi][sub + stride][ib];
                bool ta = (da < db) || (da == db && ja < jb);
                rd[k] = ta ? da : db; ri[k] = ta ? ja : jb;
                ia += ta ? 1 : 0; ib += ta ? 0 : 1;
            }
#pragma unroll
            for (int k = 0; k < KNN; ++k) { cd[qi][sub][k] = rd[k]; ci[qi][sub][k] = ri[k]; }
        }
        __syncthreads();
    }

    if (sub == 0) {
        long base = iofs + ((long)(b * NN + n)) * KNN;
        int i0 = ci[qi][0][0];
#pragma unroll
        for (int k = 0; k < KNN; ++k) {
            float d = cd[qi][0][k]; int j = ci[qi][0][k];
            idx1[base + k] = (d <= r2a) ? j : i0;
            idx2[base + k] = (d <= r2b) ? j : i0;
            idx3[base + k] = (d <= r2c) ? j : i0;
        }
    }
}

// ---------------------------------------------------------------------------
// One-time weight conversion: W{1,2,3}n -> TRANSPOSED hi/lo bf16 (B-fragment
// layout: Wt[n][k], k contiguous). hi = RNE(bf16), lo = RNE(x - hi).
// ---------------------------------------------------------------------------
__global__ __launch_bounds__(256) void convW_kernel(
        const float* __restrict__ W1, const float* __restrict__ W2,
        const float* __restrict__ W3,
        ushort* __restrict__ w1h, ushort* __restrict__ w1l,
        ushort* __restrict__ w2h, ushort* __restrict__ w2l,
        ushort* __restrict__ w3h, ushort* __restrict__ w3l) {
    int t = blockIdx.x * 256 + threadIdx.x;
    if (t < 4096) {
        int n = t >> 6, k = t & 63;
        float v = W1[(3 + k) * 64 + n];
        ushort h = f2b(v);
        w1h[t] = h; w1l[t] = f2b(v - b2f(h));
    } else if (t < 20480) {
        int u = t - 4096; int n = u >> 7, k = u & 127;
        float v = W2[(67 + k) * 128 + n];
        ushort h = f2b(v);
        w2h[u] = h; w2l[u] = f2b(v - b2f(h));
    } else if (t < 86016) {
        int u = t - 20480; int n = u >> 8, k = u & 255;
        float v = W3[(131 + k) * 256 + n];
        ushort h = f2b(v);
        w3h[u] = h; w3l[u] = f2b(v - b2f(h));
    }
}

// ---------------------------------------------------------------------------
// Kernel A: gathers + combines + bases + head. Writes s1/s2/s3 as split-bf16
// (hi/lo, row-major = MFMA A-fragment-friendly) for the MFMA G-GEMM.
// ---------------------------------------------------------------------------
template<bool FIRST>
__global__ __launch_bounds__(512, 4) void cells_kernel(
        const float* __restrict__ xq, int xq_bs,
        const float* __restrict__ xs, int xs_bs,
        const int* __restrict__ i1, const int* __restrict__ i2,
        const int* __restrict__ i3,
        const float* __restrict__ G1p, const float* __restrict__ G2p,
        const float* __restrict__ G3p,
        ushort* __restrict__ s1h, ushort* __restrict__ s1l,
        ushort* __restrict__ s2h, ushort* __restrict__ s2l,
        ushort* __restrict__ s3h, ushort* __restrict__ s3l,
        const float* __restrict__ W1, const float* __restrict__ b1,
        const float* __restrict__ W2, const float* __restrict__ b2,
        const float* __restrict__ W3, const float* __restrict__ b3,
        const float* __restrict__ Wm, const float* __restrict__ bm,
        const float* __restrict__ Wl, const float* __restrict__ bl,
        float* __restrict__ xnext, int xn_bs, int do_head) {
    __shared__ float s1s[PB][64];
    __shared__ float s2s[PB][128];
    __shared__ float s3b[PB][256];
    __shared__ float hs[PB][64];
    __shared__ float dsp[3][PB][KNN][3];
    __shared__ int   jss[3][PB][KNN];

    const int tid = threadIdx.x;
    const int blk = blockIdx.x;          // 0..511
    const int b   = blk >> 5;
    const int n0  = (blk & 31) << 4;
    const long row0 = (long)b * NN + n0;
    const long bN = (long)b * NN;

    // P0: neighbor indices + displacements for all 3 radii
    for (int t = tid; t < 3 * PB * KNN; t += 512) {
        int r = t >> 7, rem = t & 127, p = rem >> 3, k = rem & 7;
        const int* ix = (r == 0) ? i1 : ((r == 1) ? i2 : i3);
        int j = ix[(row0 + p) * KNN + k];
        jss[r][p][k] = j;
        const float* sp = xs + (long)b * xs_bs + j * 3;
        const float* qp = xq + (long)b * xq_bs + (n0 + p) * 3;
        dsp[r][p][k][0] = sp[0] - qp[0];
        dsp[r][p][k][1] = sp[1] - qp[1];
        dsp[r][p][k][2] = sp[2] - qp[2];
    }
    __syncthreads();

    // P1: cell1 combine -> s1s + split-bf16 global store
    {
        int co = tid & 63, q = tid >> 6;
        float g1r[2][KNN];
        if (!FIRST) {
#pragma unroll
            for (int r = 0; r < 2; ++r)
#pragma unroll
                for (int k = 0; k < KNN; ++k)
                    g1r[r][k] = G1p[(bN + jss[0][2 * q + r][k]) * 64 + co];
        }
        float wx = W1[co], wy = W1[64 + co], wz = W1[128 + co];
        float bz = b1[co];
#pragma unroll
        for (int r = 0; r < 2; ++r) {
            int p = 2 * q + r;
            float acc = -1e30f;
#pragma unroll
            for (int k = 0; k < KNN; ++k) {
                float v = fmaf(dsp[0][p][k][0], wx, bz);
                v = fmaf(dsp[0][p][k][1], wy, v);
                v = fmaf(dsp[0][p][k][2], wz, v);
                if (!FIRST) v += g1r[r][k];
                acc = fmaxf(acc, v);
            }
            s1s[p][co] = acc;
            ushort h = f2b(acc);
            s1h[(row0 + p) * 64 + co] = h;
            s1l[(row0 + p) * 64 + co] = f2b(acc - b2f(h));
        }
    }
    __syncthreads();

    // G2 gathers prefetched here, consumed in combine2
    float4 g2r[KNN];
    {
        int c4 = tid & 31, g = tid >> 5;
        if (!FIRST) {
#pragma unroll
            for (int k = 0; k < KNN; ++k)
                g2r[k] = ((const float4*)G2p)[(bN + jss[1][g][k]) * 32 + c4];
        }
    }

    // P2+P3: base2 then combine2 in registers -> s2s + split-bf16 store
    {
        int c4 = tid & 31, g = tid >> 5;
        const float4* W2f4 = (const float4*)(W2 + 3 * 128);
        float4 acc = ((const float4*)b2)[c4];
#pragma unroll 2
        for (int c = 0; c < 64; c += 4) {
            float4 x = *(const float4*)&s1s[g][c];
            float4 w0 = W2f4[(c + 0) * 32 + c4];
            float4 w1 = W2f4[(c + 1) * 32 + c4];
            float4 w2 = W2f4[(c + 2) * 32 + c4];
            float4 w3 = W2f4[(c + 3) * 32 + c4];
            acc.x = fmaf(x.x, w0.x, acc.x); acc.y = fmaf(x.x, w0.y, acc.y);
            acc.z = fmaf(x.x, w0.z, acc.z); acc.w = fmaf(x.x, w0.w, acc.w);
            acc.x = fmaf(x.y, w1.x, acc.x); acc.y = fmaf(x.y, w1.y, acc.y);
            acc.z = fmaf(x.y, w1.z, acc.z); acc.w = fmaf(x.y, w1.w, acc.w);
            acc.x = fmaf(x.z, w2.x, acc.x); acc.y = fmaf(x.z, w2.y, acc.y);
            acc.z = fmaf(x.z, w2.z, acc.z); acc.w = fmaf(x.z, w2.w, acc.w);
            acc.x = fmaf(x.w, w3.x, acc.x); acc.y = fmaf(x.w, w3.y, acc.y);
            acc.z = fmaf(x.w, w3.z, acc.z); acc.w = fmaf(x.w, w3.w, acc.w);
        }
        float4 wx = ((const float4*)W2)[c4];
        float4 wy = ((const float4*)(W2 + 128))[c4];
        float4 wz = ((const float4*)(W2 + 256))[c4];
        float4 m = make_float4(-1e30f, -1e30f, -1e30f, -1e30f);
#pragma unroll
        for (int k = 0; k < KNN; ++k) {
            float dx = dsp[1][g][k][0], dy = dsp[1][g][k][1], dz = dsp[1][g][k][2];
            float4 v;
            v.x = fmaf(dz, wz.x, fmaf(dy, wy.x, fmaf(dx, wx.x, acc.x)));
            v.y = fmaf(dz, wz.y, fmaf(dy, wy.y, fmaf(dx, wx.y, acc.y)));
            v.z = fmaf(dz, wz.z, fmaf(dy, wy.z, fmaf(dx, wx.z, acc.z)));
            v.w = fmaf(dz, wz.w, fmaf(dy, wy.w, fmaf(dx, wx.w, acc.w)));
            if (!FIRST) {
                v.x += g2r[k].x; v.y += g2r[k].y;
                v.z += g2r[k].z; v.w += g2r[k].w;
            }
            m.x = fmaxf(m.x, v.x); m.y = fmaxf(m.y, v.y);
            m.z = fmaxf(m.z, v.z); m.w = fmaxf(m.w, v.w);
        }
        *(float4*)&s2s[g][c4 * 4] = m;
        ushort4 mh, ml;
        mh.x = f2b(m.x); ml.x = f2b(m.x - b2f(mh.x));
        mh.y = f2b(m.y); ml.y = f2b(m.y - b2f(mh.y));
        mh.z = f2b(m.z); ml.z = f2b(m.z - b2f(mh.z));
        mh.w = f2b(m.w); ml.w = f2b(m.w - b2f(mh.w));
        *(ushort4*)&s2h[(row0 + g) * 128 + c4 * 4] = mh;
        *(ushort4*)&s2l[(row0 + g) * 128 + c4 * 4] = ml;
    }
    __syncthreads();

    // G3 gathers prefetched here, consumed in combine3
    float4 g3r[2][KNN];
    {
        int c4 = tid & 63, g = tid >> 6;
        if (!FIRST) {
#pragma unroll
            for (int r = 0; r < 2; ++r)
#pragma unroll
                for (int k = 0; k < KNN; ++k)
                    g3r[r][k] = ((const float4*)G3p)[(bN + jss[2][2 * g + r][k]) * 64 + c4];
        }
    }

    // P4+P5: base3 then combine3 in registers -> s3b + split-bf16 store
    {
        int c4 = tid & 63, g = tid >> 6;
        const float4* W3f4 = (const float4*)(W3 + 3 * 256);
        float4 bz4 = ((const float4*)b3)[c4];
        float4 a0 = bz4, a1 = bz4;
#pragma unroll 2
        for (int c = 0; c < 128; c += 4) {
            float4 x0 = *(const float4*)&s2s[2 * g][c];
            float4 x1 = *(const float4*)&s2s[2 * g + 1][c];
            float4 w0 = W3f4[(c + 0) * 64 + c4];
            float4 w1 = W3f4[(c + 1) * 64 + c4];
            float4 w2 = W3f4[(c + 2) * 64 + c4];
            float4 w3 = W3f4[(c + 3) * 64 + c4];
            a0.x = fmaf(x0.x, w0.x, a0.x); a0.y = fmaf(x0.x, w0.y, a0.y);
            a0.z = fmaf(x0.x, w0.z, a0.z); a0.w = fmaf(x0.x, w0.w, a0.w);
            a1.x = fmaf(x1.x, w0.x, a1.x); a1.y = fmaf(x1.x, w0.y, a1.y);
            a1.z = fmaf(x1.x, w0.z, a1.z); a1.w = fmaf(x1.x, w0.w, a1.w);
            a0.x = fmaf(x0.y, w1.x, a0.x); a0.y = fmaf(x0.y, w1.y, a0.y);
            a0.z = fmaf(x0.y, w1.z, a0.z); a0.w = fmaf(x0.y, w1.w, a0.w);
            a1.x = fmaf(x1.y, w1.x, a1.x); a1.y = fmaf(x1.y, w1.y, a1.y);
            a1.z = fmaf(x1.y, w1.z, a1.z); a1.w = fmaf(x1.y, w1.w, a1.w);
            a0.x = fmaf(x0.z, w2.x, a0.x); a0.y = fmaf(x0.z, w2.y, a0.y);
            a0.z = fmaf(x0.z, w2.z, a0.z); a0.w = fmaf(x0.z, w2.w, a0.w);
            a1.x = fmaf(x1.z, w2.x, a1.x); a1.y = fmaf(x1.z, w2.y, a1.y);
            a1.z = fmaf(x1.z, w2.z, a1.z); a1.w = fmaf(x1.z, w2.w, a1.w);
            a0.x = fmaf(x0.w, w3.x, a0.x); a0.y = fmaf(x0.w, w3.y, a0.y);
            a0.z = fmaf(x0.w, w3.z, a0.z); a0.w = fmaf(x0.w, w3.w, a0.w);
            a1.x = fmaf(x1.w, w3.x, a1.x); a1.y = fmaf(x1.w, w3.y, a1.y);
            a1.z = fmaf(x1.w, w3.z, a1.z); a1.w = fmaf(x1.w, w3.w, a1.w);
        }
        float4 wx = ((const float4*)W3)[c4];
        float4 wy = ((const float4*)(W3 + 256))[c4];
        float4 wz = ((const float4*)(W3 + 512))[c4];
#pragma unroll
        for (int r = 0; r < 2; ++r) {
            int p = 2 * g + r;
            float4 bse = r ? a1 : a0;
            float4 m = make_float4(-1e30f, -1e30f, -1e30f, -1e30f);
#pragma unroll
            for (int k = 0; k < KNN; ++k) {
                float dx = dsp[2][p][k][0], dy = dsp[2][p][k][1], dz = dsp[2][p][k][2];
                float4 v;
                v.x = fmaf(dz, wz.x, fmaf(dy, wy.x, fmaf(dx, wx.x, bse.x)));
                v.y = fmaf(dz, wz.y, fmaf(dy, wy.y, fmaf(dx, wx.y, bse.y)));
                v.z = fmaf(dz, wz.z, fmaf(dy, wy.z, fmaf(dx, wx.z, bse.z)));
                v.w = fmaf(dz, wz.w, fmaf(dy, wy.w, fmaf(dx, wx.w, bse.w)));
                if (!FIRST) {
                    v.x += g3r[r][k].x; v.y += g3r[r][k].y;
                    v.z += g3r[r][k].z; v.w += g3r[r][k].w;
                }
                m.x = fmaxf(m.x, v.x); m.y = fmaxf(m.y, v.y);
                m.z = fmaxf(m.z, v.z); m.w = fmaxf(m.w, v.w);
            }
            *(float4*)&s3b[p][c4 * 4] = m;
            ushort4 mh, ml;
            mh.x = f2b(m.x); ml.x = f2b(m.x - b2f(mh.x));
            mh.y = f2b(m.y); ml.y = f2b(m.y - b2f(mh.y));
            mh.z = f2b(m.z); ml.z = f2b(m.z - b2f(mh.z));
            mh.w = f2b(m.w); ml.w = f2b(m.w - b2f(mh.w));
            *(ushort4*)&s3h[(row0 + p) * 256 + c4 * 4] = mh;
            *(ushort4*)&s3l[(row0 + p) * 256 + c4 * 4] = ml;
        }
    }

    // P6: prediction head
    if (do_head) {
        __syncthreads();
        {
            int co = tid & 63, q = tid >> 6;
            float a0 = bm[co], a1 = a0;
#pragma unroll 2
            for (int c = 0; c < 256; c += 4) {
                float4 x0 = *(const float4*)&s3b[2 * q][c];
                float4 x1 = *(const float4*)&s3b[2 * q + 1][c];
                float w0 = Wm[(c + 0) * 64 + co], w1 = Wm[(c + 1) * 64 + co];
                float w2 = Wm[(c + 2) * 64 + co], w3 = Wm[(c + 3) * 64 + co];
                a0 = fmaf(x0.x, w0, a0); a0 = fmaf(x0.y, w1, a0);
                a0 = fmaf(x0.z, w2, a0); a0 = fmaf(x0.w, w3, a0);
                a1 = fmaf(x1.x, w0, a1); a1 = fmaf(x1.y, w1, a1);
                a1 = fmaf(x1.z, w2, a1); a1 = fmaf(x1.w, w3, a1);
            }
            hs[2 * q][co] = fmaxf(a0, 0.f);
            hs[2 * q + 1][co] = fmaxf(a1, 0.f);
        }
        __syncthreads();
        if (tid < PB * 3) {
            int p = tid / 3, d = tid % 3;
            float m = bl[d];
#pragma unroll 4
            for (int c = 0; c < 64; ++c)
                m = fmaf(hs[p][c], Wl[c * 3 + d], m);
            const float* qp = xq + (long)b * xq_bs + (n0 + p) * 3;
            xnext[(long)b * xn_bs + (n0 + p) * 3 + d] = qp[d] + m;
        }
    }
}

// ---------------------------------------------------------------------------
// Kernel B: G-GEMMs on the MATRIX pipe. Split-bf16: G = Ah@Bh + Ah@Bl + Al@Bh
// (fp32 acc). Wave owns 16 rows x all N cols; mfma_f32_16x16x32_bf16.
// A layout: row-major [8192][N] bf16 (lane: m=lane&15, k=quad*8+j).
// B layout: transposed [N][K] bf16 (lane: n=lane&15, k=quad*8+j).
// C/D: col=lane&15, row=quad*4+reg (verified mapping).
// ---------------------------------------------------------------------------
template<int N>
__device__ __forceinline__ void gemmT(
        const ushort* __restrict__ Ah, const ushort* __restrict__ Al,
        const ushort* __restrict__ Bh, const ushort* __restrict__ Bl,
        float* __restrict__ G, int rb, int wv, int lane) {
    constexpr int NT = N / 16;
    const int m0 = rb * 64 + wv * 16;
    const int row = lane & 15, quad = lane >> 4;
    f4_t acc[NT];
#pragma unroll
    for (int nt = 0; nt < NT; ++nt) acc[nt] = (f4_t){0.f, 0.f, 0.f, 0.f};
    const ushort* arh = Ah + (long)(m0 + row) * N + quad * 8;
    const ushort* arl = Al + (long)(m0 + row) * N + quad * 8;
    const ushort* brh = Bh + (long)row * N + quad * 8;
    const ushort* brl = Bl + (long)row * N + quad * 8;
    for (int k0 = 0; k0 < N; k0 += 32) {
        bf8_t ah = *(const bf8_t*)(arh + k0);
        bf8_t al = *(const bf8_t*)(arl + k0);
#pragma unroll
        for (int nt = 0; nt < NT; ++nt) {
            bf8_t bh = *(const bf8_t*)(brh + (long)nt * 16 * N + k0);
            bf8_t bl = *(const bf8_t*)(brl + (long)nt * 16 * N + k0);
            acc[nt] = __builtin_amdgcn_mfma_f32_16x16x32_bf16(ah, bh, acc[nt], 0, 0, 0);
            acc[nt] = __builtin_amdgcn_mfma_f32_16x16x32_bf16(ah, bl, acc[nt], 0, 0, 0);
            acc[nt] = __builtin_amdgcn_mfma_f32_16x16x32_bf16(al, bh, acc[nt], 0, 0, 0);
        }
    }
#pragma unroll
    for (int nt = 0; nt < NT; ++nt) {
        int col = nt * 16 + row;
#pragma unroll
        for (int r = 0; r < 4; ++r)
            G[(long)(m0 + quad * 4 + r) * N + col] = acc[nt][r];
    }
}

__global__ __launch_bounds__(256) void gemmG_kernel(
        const ushort* __restrict__ s1h, const ushort* __restrict__ s1l,
        const ushort* __restrict__ s2h, const ushort* __restrict__ s2l,
        const ushort* __restrict__ s3h, const ushort* __restrict__ s3l,
        const ushort* __restrict__ w1h, const ushort* __restrict__ w1l,
        const ushort* __restrict__ w2h, const ushort* __restrict__ w2l,
        const ushort* __restrict__ w3h, const ushort* __restrict__ w3l,
        float* __restrict__ G1, float* __restrict__ G2,
        float* __restrict__ G3) {
    int bx = blockIdx.x;
    int wv = threadIdx.x >> 6, lane = threadIdx.x & 63;
    if (bx < 128)       gemmT<256>(s3h, s3l, w3h, w3l, G3, bx, wv, lane);
    else if (bx < 256)  gemmT<128>(s2h, s2l, w2h, w2l, G2, bx - 128, wv, lane);
    else                gemmT<64> (s1h, s1l, w1h, w1l, G1, bx - 256, wv, lane);
}

extern "C" void kernel_launch(void* const* d_in, const int* in_sizes, int n_in,
                              void* d_out, int out_size, void* d_ws, size_t ws_size,
                              hipStream_t stream) {
    const float* frames = (const float*)d_in[0];
    const float* W1 = (const float*)d_in[1]; const float* b1 = (const float*)d_in[2];
    const float* W2 = (const float*)d_in[3]; const float* b2 = (const float*)d_in[4];
    const float* W3 = (const float*)d_in[5]; const float* b3 = (const float*)d_in[6];
    const float* Wm = (const float*)d_in[7]; const float* bm = (const float*)d_in[8];
    const float* Wl = (const float*)d_in[9]; const float* bl = (const float*)d_in[10];
    float* out = (float*)d_out;

    const long M = (long)BB * NN;    // 8192
    float* ws = (float*)d_ws;
    float* G1b = ws; ws += M * 64;
    float* G2b = ws; ws += M * 128;
    float* G3b = ws; ws += M * 256;
    ushort* us = (ushort*)ws;
    ushort* s1h = us; us += M * 64;   ushort* s1l = us; us += M * 64;
    ushort* s2h = us; us += M * 128;  ushort* s2l = us; us += M * 128;
    ushort* s3h = us; us += M * 256;  ushort* s3l = us; us += M * 256;
    ushort* w1h = us; us += 4096;     ushort* w1l = us; us += 4096;
    ushort* w2h = us; us += 16384;    ushort* w2l = us; us += 16384;
    ushort* w3h = us; us += 65536;    ushort* w3l = us; us += 65536;
    const long BNK = M * KNN;
    int* ip = (int*)us;
    int* idx1w = ip; ip += 7 * BNK;
    int* idx2w = ip; ip += 7 * BNK;
    int* idx3w = ip; ip += 7 * BNK;

    double ra = 4.0 + 1e-6, rb = 8.0 + 1e-6, rc = 12.0 + 1e-6;
    float r2a = (float)(ra * ra), r2b = (float)(rb * rb), r2c = (float)(rc * rc);

    const int FB = SEQ * NN * 3;
    const int OB = 6 * NN * 3;

    convW_kernel<<<336, 256, 0, stream>>>(W1, W2, W3,
                                          w1h, w1l, w2h, w2l, w3h, w3l);
    knn_kernel<<<dim3(NN / QB, BB, 7), 256, 0, stream>>>(
        frames, FB, nullptr, 0, idx1w, idx2w, idx3w, r2a, r2b, r2c, 1);

    for (int t = 0; t < SEQ; ++t) {
        const float* xq; int xq_bs;
        const float* xs; int xs_bs;
        if (t < 6)       { xq = frames + (long)t * NN * 3;        xq_bs = FB; }
        else if (t == 6) { xq = frames + 5L * NN * 3;             xq_bs = FB; }
        else             { xq = out + (long)(t - 7) * NN * 3;     xq_bs = OB; }
        if (t == 0)      { xs = xq;                               xs_bs = xq_bs; }
        else if (t <= 6) { xs = frames + (long)(t - 1) * NN * 3;  xs_bs = FB; }
        else if (t == 7) { xs = frames + 5L * NN * 3;             xs_bs = FB; }
        else             { xs = out + (long)(t - 8) * NN * 3;     xs_bs = OB; }

        int slot = (t <= 6) ? t : 0;
        int* i1 = idx1w + slot * BNK;
        int* i2 = idx2w + slot * BNK;
        int* i3 = idx3w + slot * BNK;

        if (t >= 7)
            knn_kernel<<<dim3(NN / QB, BB, 1), 256, 0, stream>>>(
                xq, xq_bs, xs, xs_bs, i1, i2, i3, r2a, r2b, r2c, 0);

        int do_head = (t >= 6);
        float* xnext = do_head ? out + (long)(t - 6) * NN * 3 : nullptr;

        if (t == 0)
            cells_kernel<true><<<BB * NN / PB, 512, 0, stream>>>(
                xq, xq_bs, xs, xs_bs, i1, i2, i3,
                G1b, G2b, G3b, s1h, s1l, s2h, s2l, s3h, s3l,
                W1, b1, W2, b2, W3, b3, Wm, bm, Wl, bl,
                xnext, OB, do_head);
        else
            cells_kernel<false><<<BB * NN / PB, 512, 0, stream>>>(
                xq, xq_bs, xs, xs_bs, i1, i2, i3,
                G1b, G2b, G3b, s1h, s1l, s2h, s2l, s3h, s3l,
                W1, b1, W2, b2, W3, b3, Wm, bm, Wl, bl,
                xnext, OB, do_head);

        // G for step t+1 on the matrix pipe
        if (t < SEQ - 1)
            gemmG_kernel<<<384, 256, 0, stream>>>(
                s1h, s1l, s2h, s2l, s3h, s3l,
                w1h, w1l, w2h, w2l, w3h, w3l,
                G1b, G2b, G3b);
    }
}

// Round 9
// 800.765 us; speedup vs baseline: 1.6064x; 1.6064x over previous
//
#include <hip/hip_runtime.h>
#include <math.h>

#define BB 16
#define NN 512
#define KNN 8
#define SEQ 12
#define TQ 8            // knn: threads per query
#define QB 32           // knn: queries per block (TQ*QB = 256 threads)
#define PB 16           // cells: points per block

typedef __attribute__((ext_vector_type(8))) short bf8_t;   // 8 bf16 (4 VGPRs)
typedef __attribute__((ext_vector_type(4))) float f4_t;    // MFMA acc

__device__ __forceinline__ ushort f2b(float x) {           // fp32 -> bf16 RNE
    uint u = __float_as_uint(x);
    return (ushort)((u + 0x7fffu + ((u >> 16) & 1u)) >> 16);
}
__device__ __forceinline__ float b2f(ushort h) {
    return __uint_as_float((uint)h << 16);
}

// ---------------------------------------------------------------------------
// KNN (unchanged — verified correct, conflict-free layout).
// ---------------------------------------------------------------------------
__global__ __launch_bounds__(256) void knn_kernel(
        const float* __restrict__ xq, int xq_bs,
        const float* __restrict__ xs, int xs_bs,
        int* __restrict__ idx1, int* __restrict__ idx2, int* __restrict__ idx3,
        float r2a, float r2b, float r2c, int warm) {
    __shared__ float s[NN * 3 + NN / 64];
    __shared__ float cd[QB][TQ][KNN + 1];
    __shared__ int   ci[QB][TQ][KNN + 1];
    int b = blockIdx.y;
    const float* xqp; const float* xsp; long iofs;
    if (warm) {
        int z = blockIdx.z;
        int qz = z < 5 ? z : 5;
        int sz = z - 1 < 0 ? 0 : z - 1;
        xqp = xq + (long)qz * NN * 3;
        xsp = xq + (long)sz * NN * 3;
        xs_bs = xq_bs;
        iofs = (long)z * BB * NN * KNN;
    } else {
        xqp = xq; xsp = xs; iofs = 0;
    }

    for (int j = threadIdx.x; j < NN; j += 256) {
        const float* p = xsp + (long)b * xs_bs + j * 3;
        int o = 3 * j + (j >> 6);
        s[o + 0] = p[0]; s[o + 1] = p[1]; s[o + 2] = p[2];
    }
    __syncthreads();

    int qi  = threadIdx.x / TQ;
    int sub = threadIdx.x % TQ;
    int n = blockIdx.x * QB + qi;
    const float* q = xqp + (long)b * xq_bs + n * 3;
    float qx = q[0], qy = q[1], qz2 = q[2];

    float bd[KNN];
    int   bi[KNN];
#pragma unroll
    for (int k = 0; k < KNN; ++k) { bd[k] = 1e30f; bi[k] = 0; }

    int j0 = sub * (NN / TQ);
    int sbase = 3 * j0 + sub;
#pragma unroll 4
    for (int jj = 0; jj < NN / TQ; ++jj) {
        float dx = s[sbase + 3 * jj + 0] - qx;
        float dy = s[sbase + 3 * jj + 1] - qy;
        float dz = s[sbase + 3 * jj + 2] - qz2;
        float d2 = fmaf(dx, dx, fmaf(dy, dy, dz * dz));
        if (d2 < bd[KNN - 1]) {
            bd[KNN - 1] = d2; bi[KNN - 1] = j0 + jj;
#pragma unroll
            for (int k = KNN - 1; k >= 1; --k) {
                if (bd[k] < bd[k - 1]) {
                    float td = bd[k]; bd[k] = bd[k - 1]; bd[k - 1] = td;
                    int   ti = bi[k]; bi[k] = bi[k - 1]; bi[k - 1] = ti;
                }
            }
        }
    }

#pragma unroll
    for (int k = 0; k < KNN; ++k) { cd[qi][sub][k] = bd[k]; ci[qi][sub][k] = bi[k]; }
    cd[qi][sub][KNN] = 1e30f; ci[qi][sub][KNN] = 0x7fffffff;
    __syncthreads();

    for (int stride = TQ / 2; stride >= 1; stride >>= 1) {
        if (sub < stride) {
            float rd[KNN]; int ri[KNN];
            int ia = 0, ib = 0;
#pragma unroll
            for (int k = 0; k < KNN; ++k) {
                float da = cd[qi][sub][ia], db = cd[qi][sub + stride][ib];
                int   ja = ci[qi][sub][ia], jb = ci[qi][sub + stride][ib];
                bool ta = (da < db) || (da == db && ja < jb);
                rd[k] = ta ? da : db; ri[k] = ta ? ja : jb;
                ia += ta ? 1 : 0; ib += ta ? 0 : 1;
            }
#pragma unroll
            for (int k = 0; k < KNN; ++k) { cd[qi][sub][k] = rd[k]; ci[qi][sub][k] = ri[k]; }
        }
        __syncthreads();
    }

    if (sub == 0) {
        long base = iofs + ((long)(b * NN + n)) * KNN;
        int i0 = ci[qi][0][0];
#pragma unroll
        for (int k = 0; k < KNN; ++k) {
            float d = cd[qi][0][k]; int j = ci[qi][0][k];
            idx1[base + k] = (d <= r2a) ? j : i0;
            idx2[base + k] = (d <= r2b) ? j : i0;
            idx3[base + k] = (d <= r2c) ? j : i0;
        }
    }
}

// ---------------------------------------------------------------------------
// One-time weight conversion: W{1,2,3}n -> TRANSPOSED hi/lo bf16 (B-fragment
// layout: Wt[n][k], k contiguous). hi = RNE(bf16), lo = RNE(x - hi).
// ---------------------------------------------------------------------------
__global__ __launch_bounds__(256) void convW_kernel(
        const float* __restrict__ W1, const float* __restrict__ W2,
        const float* __restrict__ W3,
        ushort* __restrict__ w1h, ushort* __restrict__ w1l,
        ushort* __restrict__ w2h, ushort* __restrict__ w2l,
        ushort* __restrict__ w3h, ushort* __restrict__ w3l) {
    int t = blockIdx.x * 256 + threadIdx.x;
    if (t < 4096) {
        int n = t >> 6, k = t & 63;
        float v = W1[(3 + k) * 64 + n];
        ushort h = f2b(v);
        w1h[t] = h; w1l[t] = f2b(v - b2f(h));
    } else if (t < 20480) {
        int u = t - 4096; int n = u >> 7, k = u & 127;
        float v = W2[(67 + k) * 128 + n];
        ushort h = f2b(v);
        w2h[u] = h; w2l[u] = f2b(v - b2f(h));
    } else if (t < 86016) {
        int u = t - 20480; int n = u >> 8, k = u & 255;
        float v = W3[(131 + k) * 256 + n];
        ushort h = f2b(v);
        w3h[u] = h; w3l[u] = f2b(v - b2f(h));
    }
}

// ---------------------------------------------------------------------------
// Kernel A: gathers + combines + bases + head (unchanged from round 8).
// ---------------------------------------------------------------------------
template<bool FIRST>
__global__ __launch_bounds__(512, 4) void cells_kernel(
        const float* __restrict__ xq, int xq_bs,
        const float* __restrict__ xs, int xs_bs,
        const int* __restrict__ i1, const int* __restrict__ i2,
        const int* __restrict__ i3,
        const float* __restrict__ G1p, const float* __restrict__ G2p,
        const float* __restrict__ G3p,
        ushort* __restrict__ s1h, ushort* __restrict__ s1l,
        ushort* __restrict__ s2h, ushort* __restrict__ s2l,
        ushort* __restrict__ s3h, ushort* __restrict__ s3l,
        const float* __restrict__ W1, const float* __restrict__ b1,
        const float* __restrict__ W2, const float* __restrict__ b2,
        const float* __restrict__ W3, const float* __restrict__ b3,
        const float* __restrict__ Wm, const float* __restrict__ bm,
        const float* __restrict__ Wl, const float* __restrict__ bl,
        float* __restrict__ xnext, int xn_bs, int do_head) {
    __shared__ float s1s[PB][64];
    __shared__ float s2s[PB][128];
    __shared__ float s3b[PB][256];
    __shared__ float hs[PB][64];
    __shared__ float dsp[3][PB][KNN][3];
    __shared__ int   jss[3][PB][KNN];

    const int tid = threadIdx.x;
    const int blk = blockIdx.x;          // 0..511
    const int b   = blk >> 5;
    const int n0  = (blk & 31) << 4;
    const long row0 = (long)b * NN + n0;
    const long bN = (long)b * NN;

    // P0: neighbor indices + displacements for all 3 radii
    for (int t = tid; t < 3 * PB * KNN; t += 512) {
        int r = t >> 7, rem = t & 127, p = rem >> 3, k = rem & 7;
        const int* ix = (r == 0) ? i1 : ((r == 1) ? i2 : i3);
        int j = ix[(row0 + p) * KNN + k];
        jss[r][p][k] = j;
        const float* sp = xs + (long)b * xs_bs + j * 3;
        const float* qp = xq + (long)b * xq_bs + (n0 + p) * 3;
        dsp[r][p][k][0] = sp[0] - qp[0];
        dsp[r][p][k][1] = sp[1] - qp[1];
        dsp[r][p][k][2] = sp[2] - qp[2];
    }
    __syncthreads();

    // P1: cell1 combine -> s1s + split-bf16 global store
    {
        int co = tid & 63, q = tid >> 6;
        float g1r[2][KNN];
        if (!FIRST) {
#pragma unroll
            for (int r = 0; r < 2; ++r)
#pragma unroll
                for (int k = 0; k < KNN; ++k)
                    g1r[r][k] = G1p[(bN + jss[0][2 * q + r][k]) * 64 + co];
        }
        float wx = W1[co], wy = W1[64 + co], wz = W1[128 + co];
        float bz = b1[co];
#pragma unroll
        for (int r = 0; r < 2; ++r) {
            int p = 2 * q + r;
            float acc = -1e30f;
#pragma unroll
            for (int k = 0; k < KNN; ++k) {
                float v = fmaf(dsp[0][p][k][0], wx, bz);
                v = fmaf(dsp[0][p][k][1], wy, v);
                v = fmaf(dsp[0][p][k][2], wz, v);
                if (!FIRST) v += g1r[r][k];
                acc = fmaxf(acc, v);
            }
            s1s[p][co] = acc;
            ushort h = f2b(acc);
            s1h[(row0 + p) * 64 + co] = h;
            s1l[(row0 + p) * 64 + co] = f2b(acc - b2f(h));
        }
    }
    __syncthreads();

    // G2 gathers prefetched here, consumed in combine2
    float4 g2r[KNN];
    {
        int c4 = tid & 31, g = tid >> 5;
        if (!FIRST) {
#pragma unroll
            for (int k = 0; k < KNN; ++k)
                g2r[k] = ((const float4*)G2p)[(bN + jss[1][g][k]) * 32 + c4];
        }
    }

    // P2+P3: base2 then combine2 in registers -> s2s + split-bf16 store
    {
        int c4 = tid & 31, g = tid >> 5;
        const float4* W2f4 = (const float4*)(W2 + 3 * 128);
        float4 acc = ((const float4*)b2)[c4];
#pragma unroll 2
        for (int c = 0; c < 64; c += 4) {
            float4 x = *(const float4*)&s1s[g][c];
            float4 w0 = W2f4[(c + 0) * 32 + c4];
            float4 w1 = W2f4[(c + 1) * 32 + c4];
            float4 w2 = W2f4[(c + 2) * 32 + c4];
            float4 w3 = W2f4[(c + 3) * 32 + c4];
            acc.x = fmaf(x.x, w0.x, acc.x); acc.y = fmaf(x.x, w0.y, acc.y);
            acc.z = fmaf(x.x, w0.z, acc.z); acc.w = fmaf(x.x, w0.w, acc.w);
            acc.x = fmaf(x.y, w1.x, acc.x); acc.y = fmaf(x.y, w1.y, acc.y);
            acc.z = fmaf(x.y, w1.z, acc.z); acc.w = fmaf(x.y, w1.w, acc.w);
            acc.x = fmaf(x.z, w2.x, acc.x); acc.y = fmaf(x.z, w2.y, acc.y);
            acc.z = fmaf(x.z, w2.z, acc.z); acc.w = fmaf(x.z, w2.w, acc.w);
            acc.x = fmaf(x.w, w3.x, acc.x); acc.y = fmaf(x.w, w3.y, acc.y);
            acc.z = fmaf(x.w, w3.z, acc.z); acc.w = fmaf(x.w, w3.w, acc.w);
        }
        float4 wx = ((const float4*)W2)[c4];
        float4 wy = ((const float4*)(W2 + 128))[c4];
        float4 wz = ((const float4*)(W2 + 256))[c4];
        float4 m = make_float4(-1e30f, -1e30f, -1e30f, -1e30f);
#pragma unroll
        for (int k = 0; k < KNN; ++k) {
            float dx = dsp[1][g][k][0], dy = dsp[1][g][k][1], dz = dsp[1][g][k][2];
            float4 v;
            v.x = fmaf(dz, wz.x, fmaf(dy, wy.x, fmaf(dx, wx.x, acc.x)));
            v.y = fmaf(dz, wz.y, fmaf(dy, wy.y, fmaf(dx, wx.y, acc.y)));
            v.z = fmaf(dz, wz.z, fmaf(dy, wy.z, fmaf(dx, wx.z, acc.z)));
            v.w = fmaf(dz, wz.w, fmaf(dy, wy.w, fmaf(dx, wx.w, acc.w)));
            if (!FIRST) {
                v.x += g2r[k].x; v.y += g2r[k].y;
                v.z += g2r[k].z; v.w += g2r[k].w;
            }
            m.x = fmaxf(m.x, v.x); m.y = fmaxf(m.y, v.y);
            m.z = fmaxf(m.z, v.z); m.w = fmaxf(m.w, v.w);
        }
        *(float4*)&s2s[g][c4 * 4] = m;
        ushort4 mh, ml;
        mh.x = f2b(m.x); ml.x = f2b(m.x - b2f(mh.x));
        mh.y = f2b(m.y); ml.y = f2b(m.y - b2f(mh.y));
        mh.z = f2b(m.z); ml.z = f2b(m.z - b2f(mh.z));
        mh.w = f2b(m.w); ml.w = f2b(m.w - b2f(mh.w));
        *(ushort4*)&s2h[(row0 + g) * 128 + c4 * 4] = mh;
        *(ushort4*)&s2l[(row0 + g) * 128 + c4 * 4] = ml;
    }
    __syncthreads();

    // G3 gathers prefetched here, consumed in combine3
    float4 g3r[2][KNN];
    {
        int c4 = tid & 63, g = tid >> 6;
        if (!FIRST) {
#pragma unroll
            for (int r = 0; r < 2; ++r)
#pragma unroll
                for (int k = 0; k < KNN; ++k)
                    g3r[r][k] = ((const float4*)G3p)[(bN + jss[2][2 * g + r][k]) * 64 + c4];
        }
    }

    // P4+P5: base3 then combine3 in registers -> s3b + split-bf16 store
    {
        int c4 = tid & 63, g = tid >> 6;
        const float4* W3f4 = (const float4*)(W3 + 3 * 256);
        float4 bz4 = ((const float4*)b3)[c4];
        float4 a0 = bz4, a1 = bz4;
#pragma unroll 2
        for (int c = 0; c < 128; c += 4) {
            float4 x0 = *(const float4*)&s2s[2 * g][c];
            float4 x1 = *(const float4*)&s2s[2 * g + 1][c];
            float4 w0 = W3f4[(c + 0) * 64 + c4];
            float4 w1 = W3f4[(c + 1) * 64 + c4];
            float4 w2 = W3f4[(c + 2) * 64 + c4];
            float4 w3 = W3f4[(c + 3) * 64 + c4];
            a0.x = fmaf(x0.x, w0.x, a0.x); a0.y = fmaf(x0.x, w0.y, a0.y);
            a0.z = fmaf(x0.x, w0.z, a0.z); a0.w = fmaf(x0.x, w0.w, a0.w);
            a1.x = fmaf(x1.x, w0.x, a1.x); a1.y = fmaf(x1.x, w0.y, a1.y);
            a1.z = fmaf(x1.x, w0.z, a1.z); a1.w = fmaf(x1.x, w0.w, a1.w);
            a0.x = fmaf(x0.y, w1.x, a0.x); a0.y = fmaf(x0.y, w1.y, a0.y);
            a0.z = fmaf(x0.y, w1.z, a0.z); a0.w = fmaf(x0.y, w1.w, a0.w);
            a1.x = fmaf(x1.y, w1.x, a1.x); a1.y = fmaf(x1.y, w1.y, a1.y);
            a1.z = fmaf(x1.y, w1.z, a1.z); a1.w = fmaf(x1.y, w1.w, a1.w);
            a0.x = fmaf(x0.z, w2.x, a0.x); a0.y = fmaf(x0.z, w2.y, a0.y);
            a0.z = fmaf(x0.z, w2.z, a0.z); a0.w = fmaf(x0.z, w2.w, a0.w);
            a1.x = fmaf(x1.z, w2.x, a1.x); a1.y = fmaf(x1.z, w2.y, a1.y);
            a1.z = fmaf(x1.z, w2.z, a1.z); a1.w = fmaf(x1.z, w2.w, a1.w);
            a0.x = fmaf(x0.w, w3.x, a0.x); a0.y = fmaf(x0.w, w3.y, a0.y);
            a0.z = fmaf(x0.w, w3.z, a0.z); a0.w = fmaf(x0.w, w3.w, a0.w);
            a1.x = fmaf(x1.w, w3.x, a1.x); a1.y = fmaf(x1.w, w3.y, a1.y);
            a1.z = fmaf(x1.w, w3.z, a1.z); a1.w = fmaf(x1.w, w3.w, a1.w);
        }
        float4 wx = ((const float4*)W3)[c4];
        float4 wy = ((const float4*)(W3 + 256))[c4];
        float4 wz = ((const float4*)(W3 + 512))[c4];
#pragma unroll
        for (int r = 0; r < 2; ++r) {
            int p = 2 * g + r;
            float4 bse = r ? a1 : a0;
            float4 m = make_float4(-1e30f, -1e30f, -1e30f, -1e30f);
#pragma unroll
            for (int k = 0; k < KNN; ++k) {
                float dx = dsp[2][p][k][0], dy = dsp[2][p][k][1], dz = dsp[2][p][k][2];
                float4 v;
                v.x = fmaf(dz, wz.x, fmaf(dy, wy.x, fmaf(dx, wx.x, bse.x)));
                v.y = fmaf(dz, wz.y, fmaf(dy, wy.y, fmaf(dx, wx.y, bse.y)));
                v.z = fmaf(dz, wz.z, fmaf(dy, wy.z, fmaf(dx, wx.z, bse.z)));
                v.w = fmaf(dz, wz.w, fmaf(dy, wy.w, fmaf(dx, wx.w, bse.w)));
                if (!FIRST) {
                    v.x += g3r[r][k].x; v.y += g3r[r][k].y;
                    v.z += g3r[r][k].z; v.w += g3r[r][k].w;
                }
                m.x = fmaxf(m.x, v.x); m.y = fmaxf(m.y, v.y);
                m.z = fmaxf(m.z, v.z); m.w = fmaxf(m.w, v.w);
            }
            *(float4*)&s3b[p][c4 * 4] = m;
            ushort4 mh, ml;
            mh.x = f2b(m.x); ml.x = f2b(m.x - b2f(mh.x));
            mh.y = f2b(m.y); ml.y = f2b(m.y - b2f(mh.y));
            mh.z = f2b(m.z); ml.z = f2b(m.z - b2f(mh.z));
            mh.w = f2b(m.w); ml.w = f2b(m.w - b2f(mh.w));
            *(ushort4*)&s3h[(row0 + p) * 256 + c4 * 4] = mh;
            *(ushort4*)&s3l[(row0 + p) * 256 + c4 * 4] = ml;
        }
    }

    // P6: prediction head
    if (do_head) {
        __syncthreads();
        {
            int co = tid & 63, q = tid >> 6;
            float a0 = bm[co], a1 = a0;
#pragma unroll 2
            for (int c = 0; c < 256; c += 4) {
                float4 x0 = *(const float4*)&s3b[2 * q][c];
                float4 x1 = *(const float4*)&s3b[2 * q + 1][c];
                float w0 = Wm[(c + 0) * 64 + co], w1 = Wm[(c + 1) * 64 + co];
                float w2 = Wm[(c + 2) * 64 + co], w3 = Wm[(c + 3) * 64 + co];
                a0 = fmaf(x0.x, w0, a0); a0 = fmaf(x0.y, w1, a0);
                a0 = fmaf(x0.z, w2, a0); a0 = fmaf(x0.w, w3, a0);
                a1 = fmaf(x1.x, w0, a1); a1 = fmaf(x1.y, w1, a1);
                a1 = fmaf(x1.z, w2, a1); a1 = fmaf(x1.w, w3, a1);
            }
            hs[2 * q][co] = fmaxf(a0, 0.f);
            hs[2 * q + 1][co] = fmaxf(a1, 0.f);
        }
        __syncthreads();
        if (tid < PB * 3) {
            int p = tid / 3, d = tid % 3;
            float m = bl[d];
#pragma unroll 4
            for (int c = 0; c < 64; ++c)
                m = fmaf(hs[p][c], Wl[c * 3 + d], m);
            const float* qp = xq + (long)b * xq_bs + (n0 + p) * 3;
            xnext[(long)b * xn_bs + (n0 + p) * 3 + d] = qp[d] + m;
        }
    }
}

// ---------------------------------------------------------------------------
// Kernel B: tiled MFMA GEMM. Block = 128 M x 64 N, 4 waves (each 32 M x 64 N,
// 2x4 acc tiles). Per 32-k chunk: A(128x32) and B(64x32) hi+lo staged in LDS
// (row stride 40 ushorts -> max 2-way bank aliasing = free), next chunk
// register-prefetched before MFMAs. Split-bf16: Ah@Bh + Ah@Bl + Al@Bh.
// A: row-major [M][K]; B: transposed [N][K]. C/D: col=lane&15, row=quad*4+r.
// ---------------------------------------------------------------------------
template<int N>
__device__ __forceinline__ void gemmTile(
        const ushort* __restrict__ Ah, const ushort* __restrict__ Al,
        const ushort* __restrict__ Bh, const ushort* __restrict__ Bl,
        float* __restrict__ G, int rb, int cb, int tid, ushort* lds) {
    const int row0 = rb * 128, c0 = cb * 64;
    ushort* ah = lds;
    ushort* al = lds + 128 * 40;
    ushort* bh = lds + 256 * 40;
    ushort* bl = lds + 320 * 40;
    const int wv = tid >> 6, lane = tid & 63;
    const int m = lane & 15, quad = lane >> 4;
    const int wm0 = wv * 32;
    const int lr = tid >> 2, ls = (tid & 3) * 8;   // staging row/seg

    f4_t acc[2][4];
#pragma unroll
    for (int rt = 0; rt < 2; ++rt)
#pragma unroll
        for (int ct = 0; ct < 4; ++ct) acc[rt][ct] = (f4_t){0.f, 0.f, 0.f, 0.f};

    bf8_t pah0, pah1, pal0, pal1, pbh, pbl;
    // prefetch chunk 0
    pah0 = *(const bf8_t*)(Ah + (long)(row0 + lr) * N + ls);
    pah1 = *(const bf8_t*)(Ah + (long)(row0 + 64 + lr) * N + ls);
    pal0 = *(const bf8_t*)(Al + (long)(row0 + lr) * N + ls);
    pal1 = *(const bf8_t*)(Al + (long)(row0 + 64 + lr) * N + ls);
    pbh  = *(const bf8_t*)(Bh + (long)(c0 + lr) * N + ls);
    pbl  = *(const bf8_t*)(Bl + (long)(c0 + lr) * N + ls);

    for (int k0 = 0; k0 < N; k0 += 32) {
        if (k0) __syncthreads();
        *(bf8_t*)(ah + lr * 40 + ls) = pah0;
        *(bf8_t*)(ah + (64 + lr) * 40 + ls) = pah1;
        *(bf8_t*)(al + lr * 40 + ls) = pal0;
        *(bf8_t*)(al + (64 + lr) * 40 + ls) = pal1;
        *(bf8_t*)(bh + lr * 40 + ls) = pbh;
        *(bf8_t*)(bl + lr * 40 + ls) = pbl;
        __syncthreads();
        if (k0 + 32 < N) {
            int kn = k0 + 32;
            pah0 = *(const bf8_t*)(Ah + (long)(row0 + lr) * N + kn + ls);
            pah1 = *(const bf8_t*)(Ah + (long)(row0 + 64 + lr) * N + kn + ls);
            pal0 = *(const bf8_t*)(Al + (long)(row0 + lr) * N + kn + ls);
            pal1 = *(const bf8_t*)(Al + (long)(row0 + 64 + lr) * N + kn + ls);
            pbh  = *(const bf8_t*)(Bh + (long)(c0 + lr) * N + kn + ls);
            pbl  = *(const bf8_t*)(Bl + (long)(c0 + lr) * N + kn + ls);
        }
        bf8_t a0h = *(const bf8_t*)(ah + (wm0 + m) * 40 + quad * 8);
        bf8_t a0l = *(const bf8_t*)(al + (wm0 + m) * 40 + quad * 8);
        bf8_t a1h = *(const bf8_t*)(ah + (wm0 + 16 + m) * 40 + quad * 8);
        bf8_t a1l = *(const bf8_t*)(al + (wm0 + 16 + m) * 40 + quad * 8);
#pragma unroll
        for (int ct = 0; ct < 4; ++ct) {
            bf8_t bth = *(const bf8_t*)(bh + (ct * 16 + m) * 40 + quad * 8);
            bf8_t btl = *(const bf8_t*)(bl + (ct * 16 + m) * 40 + quad * 8);
            acc[0][ct] = __builtin_amdgcn_mfma_f32_16x16x32_bf16(a0h, bth, acc[0][ct], 0, 0, 0);
            acc[0][ct] = __builtin_amdgcn_mfma_f32_16x16x32_bf16(a0h, btl, acc[0][ct], 0, 0, 0);
            acc[0][ct] = __builtin_amdgcn_mfma_f32_16x16x32_bf16(a0l, bth, acc[0][ct], 0, 0, 0);
            acc[1][ct] = __builtin_amdgcn_mfma_f32_16x16x32_bf16(a1h, bth, acc[1][ct], 0, 0, 0);
            acc[1][ct] = __builtin_amdgcn_mfma_f32_16x16x32_bf16(a1h, btl, acc[1][ct], 0, 0, 0);
            acc[1][ct] = __builtin_amdgcn_mfma_f32_16x16x32_bf16(a1l, bth, acc[1][ct], 0, 0, 0);
        }
    }
#pragma unroll
    for (int rt = 0; rt < 2; ++rt)
#pragma unroll
        for (int ct = 0; ct < 4; ++ct) {
            int col = c0 + ct * 16 + m;
#pragma unroll
            for (int r = 0; r < 4; ++r)
                G[(long)(row0 + wm0 + rt * 16 + quad * 4 + r) * N + col] = acc[rt][ct][r];
        }
}

__global__ __launch_bounds__(256) void gemmG_kernel(
        const ushort* __restrict__ s1h, const ushort* __restrict__ s1l,
        const ushort* __restrict__ s2h, const ushort* __restrict__ s2l,
        const ushort* __restrict__ s3h, const ushort* __restrict__ s3l,
        const ushort* __restrict__ w1h, const ushort* __restrict__ w1l,
        const ushort* __restrict__ w2h, const ushort* __restrict__ w2l,
        const ushort* __restrict__ w3h, const ushort* __restrict__ w3l,
        float* __restrict__ G1, float* __restrict__ G2,
        float* __restrict__ G3) {
    __shared__ ushort lds[384 * 40];
    int bx = blockIdx.x, tid = threadIdx.x;
    if (bx < 256)
        gemmTile<256>(s3h, s3l, w3h, w3l, G3, bx >> 2, bx & 3, tid, lds);
    else if (bx < 384)
        gemmTile<128>(s2h, s2l, w2h, w2l, G2, (bx - 256) >> 1, (bx - 256) & 1, tid, lds);
    else
        gemmTile<64>(s1h, s1l, w1h, w1l, G1, bx - 384, 0, tid, lds);
}

extern "C" void kernel_launch(void* const* d_in, const int* in_sizes, int n_in,
                              void* d_out, int out_size, void* d_ws, size_t ws_size,
                              hipStream_t stream) {
    const float* frames = (const float*)d_in[0];
    const float* W1 = (const float*)d_in[1]; const float* b1 = (const float*)d_in[2];
    const float* W2 = (const float*)d_in[3]; const float* b2 = (const float*)d_in[4];
    const float* W3 = (const float*)d_in[5]; const float* b3 = (const float*)d_in[6];
    const float* Wm = (const float*)d_in[7]; const float* bm = (const float*)d_in[8];
    const float* Wl = (const float*)d_in[9]; const float* bl = (const float*)d_in[10];
    float* out = (float*)d_out;

    const long M = (long)BB * NN;    // 8192
    float* ws = (float*)d_ws;
    float* G1b = ws; ws += M * 64;
    float* G2b = ws; ws += M * 128;
    float* G3b = ws; ws += M * 256;
    ushort* us = (ushort*)ws;
    ushort* s1h = us; us += M * 64;   ushort* s1l = us; us += M * 64;
    ushort* s2h = us; us += M * 128;  ushort* s2l = us; us += M * 128;
    ushort* s3h = us; us += M * 256;  ushort* s3l = us; us += M * 256;
    ushort* w1h = us; us += 4096;     ushort* w1l = us; us += 4096;
    ushort* w2h = us; us += 16384;    ushort* w2l = us; us += 16384;
    ushort* w3h = us; us += 65536;    ushort* w3l = us; us += 65536;
    const long BNK = M * KNN;
    int* ip = (int*)us;
    int* idx1w = ip; ip += 7 * BNK;
    int* idx2w = ip; ip += 7 * BNK;
    int* idx3w = ip; ip += 7 * BNK;

    double ra = 4.0 + 1e-6, rb = 8.0 + 1e-6, rc = 12.0 + 1e-6;
    float r2a = (float)(ra * ra), r2b = (float)(rb * rb), r2c = (float)(rc * rc);

    const int FB = SEQ * NN * 3;
    const int OB = 6 * NN * 3;

    convW_kernel<<<336, 256, 0, stream>>>(W1, W2, W3,
                                          w1h, w1l, w2h, w2l, w3h, w3l);
    knn_kernel<<<dim3(NN / QB, BB, 7), 256, 0, stream>>>(
        frames, FB, nullptr, 0, idx1w, idx2w, idx3w, r2a, r2b, r2c, 1);

    for (int t = 0; t < SEQ; ++t) {
        const float* xq; int xq_bs;
        const float* xs; int xs_bs;
        if (t < 6)       { xq = frames + (long)t * NN * 3;        xq_bs = FB; }
        else if (t == 6) { xq = frames + 5L * NN * 3;             xq_bs = FB; }
        else             { xq = out + (long)(t - 7) * NN * 3;     xq_bs = OB; }
        if (t == 0)      { xs = xq;                               xs_bs = xq_bs; }
        else if (t <= 6) { xs = frames + (long)(t - 1) * NN * 3;  xs_bs = FB; }
        else if (t == 7) { xs = frames + 5L * NN * 3;             xs_bs = FB; }
        else             { xs = out + (long)(t - 8) * NN * 3;     xs_bs = OB; }

        int slot = (t <= 6) ? t : 0;
        int* i1 = idx1w + slot * BNK;
        int* i2 = idx2w + slot * BNK;
        int* i3 = idx3w + slot * BNK;

        if (t >= 7)
            knn_kernel<<<dim3(NN / QB, BB, 1), 256, 0, stream>>>(
                xq, xq_bs, xs, xs_bs, i1, i2, i3, r2a, r2b, r2c, 0);

        int do_head = (t >= 6);
        float* xnext = do_head ? out + (long)(t - 6) * NN * 3 : nullptr;

        if (t == 0)
            cells_kernel<true><<<BB * NN / PB, 512, 0, stream>>>(
                xq, xq_bs, xs, xs_bs, i1, i2, i3,
                G1b, G2b, G3b, s1h, s1l, s2h, s2l, s3h, s3l,
                W1, b1, W2, b2, W3, b3, Wm, bm, Wl, bl,
                xnext, OB, do_head);
        else
            cells_kernel<false><<<BB * NN / PB, 512, 0, stream>>>(
                xq, xq_bs, xs, xs_bs, i1, i2, i3,
                G1b, G2b, G3b, s1h, s1l, s2h, s2l, s3h, s3l,
                W1, b1, W2, b2, W3, b3, Wm, bm, Wl, bl,
                xnext, OB, do_head);

        // G for step t+1 on the matrix pipe
        if (t < SEQ - 1)
            gemmG_kernel<<<448, 256, 0, stream>>>(
                s1h, s1l, s2h, s2l, s3h, s3l,
                w1h, w1l, w2h, w2l, w3h, w3l,
                G1b, G2b, G3b);
    }
}

// Round 10
// 555.614 us; speedup vs baseline: 2.3152x; 1.4412x over previous
//
#include <hip/hip_runtime.h>
#include <math.h>

#define BB 16
#define NN 512
#define KNN 8
#define SEQ 12
#define TQ 8            // knn: threads per query
#define QB 32           // knn: queries per block (TQ*QB = 256 threads)
#define PB 16           // cells: points per block

typedef __attribute__((ext_vector_type(8))) short bf8_t;   // 8 bf16 (4 VGPRs)
typedef __attribute__((ext_vector_type(4))) float f4_t;    // MFMA acc

__device__ __forceinline__ ushort f2b(float x) {           // fp32 -> bf16 RNE
    uint u = __float_as_uint(x);
    return (ushort)((u + 0x7fffu + ((u >> 16) & 1u)) >> 16);
}
__device__ __forceinline__ float b2f(ushort h) {
    return __uint_as_float((uint)h << 16);
}
// 8 consecutive fp32 -> hi/lo bf16 fragments
__device__ __forceinline__ void cvt8(const float* __restrict__ p,
                                     bf8_t& h, bf8_t& l) {
    float4 x0 = *(const float4*)p;
    float4 x1 = *(const float4*)(p + 4);
    float v[8] = {x0.x, x0.y, x0.z, x0.w, x1.x, x1.y, x1.z, x1.w};
#pragma unroll
    for (int i = 0; i < 8; ++i) {
        ushort hh = f2b(v[i]);
        h[i] = (short)hh;
        l[i] = (short)f2b(v[i] - b2f(hh));
    }
}

// ---------------------------------------------------------------------------
// KNN (unchanged — verified correct, conflict-free layout).
// ---------------------------------------------------------------------------
__global__ __launch_bounds__(256) void knn_kernel(
        const float* __restrict__ xq, int xq_bs,
        const float* __restrict__ xs, int xs_bs,
        int* __restrict__ idx1, int* __restrict__ idx2, int* __restrict__ idx3,
        float r2a, float r2b, float r2c, int warm) {
    __shared__ float s[NN * 3 + NN / 64];
    __shared__ float cd[QB][TQ][KNN + 1];
    __shared__ int   ci[QB][TQ][KNN + 1];
    int b = blockIdx.y;
    const float* xqp; const float* xsp; long iofs;
    if (warm) {
        int z = blockIdx.z;
        int qz = z < 5 ? z : 5;
        int sz = z - 1 < 0 ? 0 : z - 1;
        xqp = xq + (long)qz * NN * 3;
        xsp = xq + (long)sz * NN * 3;
        xs_bs = xq_bs;
        iofs = (long)z * BB * NN * KNN;
    } else {
        xqp = xq; xsp = xs; iofs = 0;
    }

    for (int j = threadIdx.x; j < NN; j += 256) {
        const float* p = xsp + (long)b * xs_bs + j * 3;
        int o = 3 * j + (j >> 6);
        s[o + 0] = p[0]; s[o + 1] = p[1]; s[o + 2] = p[2];
    }
    __syncthreads();

    int qi  = threadIdx.x / TQ;
    int sub = threadIdx.x % TQ;
    int n = blockIdx.x * QB + qi;
    const float* q = xqp + (long)b * xq_bs + n * 3;
    float qx = q[0], qy = q[1], qz2 = q[2];

    float bd[KNN];
    int   bi[KNN];
#pragma unroll
    for (int k = 0; k < KNN; ++k) { bd[k] = 1e30f; bi[k] = 0; }

    int j0 = sub * (NN / TQ);
    int sbase = 3 * j0 + sub;
#pragma unroll 4
    for (int jj = 0; jj < NN / TQ; ++jj) {
        float dx = s[sbase + 3 * jj + 0] - qx;
        float dy = s[sbase + 3 * jj + 1] - qy;
        float dz = s[sbase + 3 * jj + 2] - qz2;
        float d2 = fmaf(dx, dx, fmaf(dy, dy, dz * dz));
        if (d2 < bd[KNN - 1]) {
            bd[KNN - 1] = d2; bi[KNN - 1] = j0 + jj;
#pragma unroll
            for (int k = KNN - 1; k >= 1; --k) {
                if (bd[k] < bd[k - 1]) {
                    float td = bd[k]; bd[k] = bd[k - 1]; bd[k - 1] = td;
                    int   ti = bi[k]; bi[k] = bi[k - 1]; bi[k - 1] = ti;
                }
            }
        }
    }

#pragma unroll
    for (int k = 0; k < KNN; ++k) { cd[qi][sub][k] = bd[k]; ci[qi][sub][k] = bi[k]; }
    cd[qi][sub][KNN] = 1e30f; ci[qi][sub][KNN] = 0x7fffffff;
    __syncthreads();

    for (int stride = TQ / 2; stride >= 1; stride >>= 1) {
        if (sub < stride) {
            float rd[KNN]; int ri[KNN];
            int ia = 0, ib = 0;
#pragma unroll
            for (int k = 0; k < KNN; ++k) {
                float da = cd[qi][sub][ia], db = cd[qi][sub + stride][ib];
                int   ja = ci[qi][sub][ia], jb = ci[qi][sub + stride][ib];
                bool ta = (da < db) || (da == db && ja < jb);
                rd[k] = ta ? da : db; ri[k] = ta ? ja : jb;
                ia += ta ? 1 : 0; ib += ta ? 0 : 1;
            }
#pragma unroll
            for (int k = 0; k < KNN; ++k) { cd[qi][sub][k] = rd[k]; ci[qi][sub][k] = ri[k]; }
        }
        __syncthreads();
    }

    if (sub == 0) {
        long base = iofs + ((long)(b * NN + n)) * KNN;
        int i0 = ci[qi][0][0];
#pragma unroll
        for (int k = 0; k < KNN; ++k) {
            float d = cd[qi][0][k]; int j = ci[qi][0][k];
            idx1[base + k] = (d <= r2a) ? j : i0;
            idx2[base + k] = (d <= r2b) ? j : i0;
            idx3[base + k] = (d <= r2c) ? j : i0;
        }
    }
}

// ---------------------------------------------------------------------------
// One-time weight conversion to transposed split-bf16 (B-fragment layout:
// Wt[n][k], k contiguous): W1n/W2n/W3n (G-GEMMs) + W2f/W3f/Wm (cells MFMA).
// ---------------------------------------------------------------------------
__global__ __launch_bounds__(256) void convW_kernel(
        const float* __restrict__ W1, const float* __restrict__ W2,
        const float* __restrict__ W3, const float* __restrict__ Wm,
        ushort* __restrict__ w1h, ushort* __restrict__ w1l,
        ushort* __restrict__ w2h, ushort* __restrict__ w2l,
        ushort* __restrict__ w3h, ushort* __restrict__ w3l,
        ushort* __restrict__ w2fh, ushort* __restrict__ w2fl,
        ushort* __restrict__ w3fh, ushort* __restrict__ w3fl,
        ushort* __restrict__ wmh, ushort* __restrict__ wml) {
    int t = blockIdx.x * 256 + threadIdx.x;
    float v; ushort* ph; ushort* pl; int idx;
    if (t < 4096)        { int n = t >> 6, k = t & 63;
        v = W1[(3 + k) * 64 + n];   ph = w1h;  pl = w1l;  idx = t; }
    else if (t < 20480)  { int u = t - 4096, n = u >> 7, k = u & 127;
        v = W2[(67 + k) * 128 + n]; ph = w2h;  pl = w2l;  idx = u; }
    else if (t < 86016)  { int u = t - 20480, n = u >> 8, k = u & 255;
        v = W3[(131 + k) * 256 + n]; ph = w3h; pl = w3l;  idx = u; }
    else if (t < 94208)  { int u = t - 86016, n = u >> 6, k = u & 63;
        v = W2[(3 + k) * 128 + n];  ph = w2fh; pl = w2fl; idx = u; }
    else if (t < 126976) { int u = t - 94208, n = u >> 7, k = u & 127;
        v = W3[(3 + k) * 256 + n];  ph = w3fh; pl = w3fl; idx = u; }
    else if (t < 143360) { int u = t - 126976, n = u >> 8, k = u & 255;
        v = Wm[k * 64 + n];         ph = wmh;  pl = wml;  idx = u; }
    else return;
    ushort h = f2b(v);
    ph[idx] = h; pl[idx] = f2b(v - b2f(h));
}

// ---------------------------------------------------------------------------
// Kernel A: gathers + combines (VALU) with base2/base3/head on MFMA.
// XCD-affinity swizzle: all blocks of batch b land on XCD b/2, so G gathers
// hit their own XCD's L2 instead of duplicating fetch across 8 XCDs.
// LDS tiles padded (+4 floats/row) to break power-of-2 A-fragment strides.
// ---------------------------------------------------------------------------
template<bool FIRST>
__global__ __launch_bounds__(512, 4) void cells_kernel(
        const float* __restrict__ xq, int xq_bs,
        const float* __restrict__ xs, int xs_bs,
        const int* __restrict__ i1, const int* __restrict__ i2,
        const int* __restrict__ i3,
        const float* __restrict__ G1p, const float* __restrict__ G2p,
        const float* __restrict__ G3p,
        ushort* __restrict__ s1h, ushort* __restrict__ s1l,
        ushort* __restrict__ s2h, ushort* __restrict__ s2l,
        ushort* __restrict__ s3h, ushort* __restrict__ s3l,
        const float* __restrict__ W1, const float* __restrict__ b1,
        const float* __restrict__ W2, const float* __restrict__ b2,
        const float* __restrict__ W3, const float* __restrict__ b3,
        const ushort* __restrict__ w2fh, const ushort* __restrict__ w2fl,
        const ushort* __restrict__ w3fh, const ushort* __restrict__ w3fl,
        const ushort* __restrict__ wmh, const ushort* __restrict__ wml,
        const float* __restrict__ bm,
        const float* __restrict__ Wl, const float* __restrict__ bl,
        float* __restrict__ xnext, int xn_bs, int do_head) {
    __shared__ float s1s[PB][68];
    __shared__ float s2s[PB][132];
    __shared__ float s3b[PB][260];
    __shared__ float hs[PB][64];
    __shared__ float dsp[3][PB][KNN][3];
    __shared__ int   jss[3][PB][KNN];

    const int tid = threadIdx.x;
    const int blk = blockIdx.x;          // 0..511
    const int xcd = blk & 7, slot = blk >> 3;
    const int b   = xcd * 2 + (slot >> 5);     // batch <-> XCD affinity
    const int n0  = (slot & 31) << 4;
    const long row0 = (long)b * NN + n0;
    const long bN = (long)b * NN;
    const int wv = tid >> 6, lane = tid & 63;
    const int fm = lane & 15, quad = lane >> 4;

    // P0: neighbor indices + displacements for all 3 radii
    for (int t = tid; t < 3 * PB * KNN; t += 512) {
        int r = t >> 7, rem = t & 127, p = rem >> 3, k = rem & 7;
        const int* ix = (r == 0) ? i1 : ((r == 1) ? i2 : i3);
        int j = ix[(row0 + p) * KNN + k];
        jss[r][p][k] = j;
        const float* sp = xs + (long)b * xs_bs + j * 3;
        const float* qp = xq + (long)b * xq_bs + (n0 + p) * 3;
        dsp[r][p][k][0] = sp[0] - qp[0];
        dsp[r][p][k][1] = sp[1] - qp[1];
        dsp[r][p][k][2] = sp[2] - qp[2];
    }
    __syncthreads();

    // P1: cell1 combine -> s1s + split-bf16 global store
    {
        int co = tid & 63, q = tid >> 6;
        float g1r[2][KNN];
        if (!FIRST) {
#pragma unroll
            for (int r = 0; r < 2; ++r)
#pragma unroll
                for (int k = 0; k < KNN; ++k)
                    g1r[r][k] = G1p[(bN + jss[0][2 * q + r][k]) * 64 + co];
        }
        float wx = W1[co], wy = W1[64 + co], wz = W1[128 + co];
        float bz = b1[co];
#pragma unroll
        for (int r = 0; r < 2; ++r) {
            int p = 2 * q + r;
            float acc = -1e30f;
#pragma unroll
            for (int k = 0; k < KNN; ++k) {
                float v = fmaf(dsp[0][p][k][0], wx, bz);
                v = fmaf(dsp[0][p][k][1], wy, v);
                v = fmaf(dsp[0][p][k][2], wz, v);
                if (!FIRST) v += g1r[r][k];
                acc = fmaxf(acc, v);
            }
            s1s[p][co] = acc;
            ushort h = f2b(acc);
            s1h[(row0 + p) * 64 + co] = h;
            s1l[(row0 + p) * 64 + co] = f2b(acc - b2f(h));
        }
    }
    __syncthreads();

    // G2 gathers prefetched (consumed in combine2, hidden behind base2 MFMA)
    float4 g2r[KNN];
    {
        int c4 = tid & 31, g = tid >> 5;
        if (!FIRST) {
#pragma unroll
            for (int k = 0; k < KNN; ++k)
                g2r[k] = ((const float4*)G2p)[(bN + jss[1][g][k]) * 32 + c4];
        }
    }

    // P2: base2 = s1 @ W2f + b2 on MFMA -> s2s (C: row=quad*4+r, col=lane&15)
    {
        int col = wv * 16 + fm;
        float bz = b2[col];
        f4_t acc = {bz, bz, bz, bz};
#pragma unroll
        for (int k0 = 0; k0 < 64; k0 += 32) {
            bf8_t ah, al; cvt8(&s1s[fm][k0 + quad * 8], ah, al);
            bf8_t bh = *(const bf8_t*)(w2fh + col * 64 + k0 + quad * 8);
            bf8_t bl = *(const bf8_t*)(w2fl + col * 64 + k0 + quad * 8);
            acc = __builtin_amdgcn_mfma_f32_16x16x32_bf16(ah, bh, acc, 0, 0, 0);
            acc = __builtin_amdgcn_mfma_f32_16x16x32_bf16(ah, bl, acc, 0, 0, 0);
            acc = __builtin_amdgcn_mfma_f32_16x16x32_bf16(al, bh, acc, 0, 0, 0);
        }
#pragma unroll
        for (int r = 0; r < 4; ++r) s2s[quad * 4 + r][col] = acc[r];
    }
    __syncthreads();

    // P3: combine2 in place on s2s + split-bf16 global store
    {
        int c4 = tid & 31, g = tid >> 5;
        float4 bse = *(float4*)&s2s[g][c4 * 4];
        float4 wx = ((const float4*)W2)[c4];
        float4 wy = ((const float4*)(W2 + 128))[c4];
        float4 wz = ((const float4*)(W2 + 256))[c4];
        float4 m = make_float4(-1e30f, -1e30f, -1e30f, -1e30f);
#pragma unroll
        for (int k = 0; k < KNN; ++k) {
            float dx = dsp[1][g][k][0], dy = dsp[1][g][k][1], dz = dsp[1][g][k][2];
            float4 v;
            v.x = fmaf(dz, wz.x, fmaf(dy, wy.x, fmaf(dx, wx.x, bse.x)));
            v.y = fmaf(dz, wz.y, fmaf(dy, wy.y, fmaf(dx, wx.y, bse.y)));
            v.z = fmaf(dz, wz.z, fmaf(dy, wy.z, fmaf(dx, wx.z, bse.z)));
            v.w = fmaf(dz, wz.w, fmaf(dy, wy.w, fmaf(dx, wx.w, bse.w)));
            if (!FIRST) {
                v.x += g2r[k].x; v.y += g2r[k].y;
                v.z += g2r[k].z; v.w += g2r[k].w;
            }
            m.x = fmaxf(m.x, v.x); m.y = fmaxf(m.y, v.y);
            m.z = fmaxf(m.z, v.z); m.w = fmaxf(m.w, v.w);
        }
        *(float4*)&s2s[g][c4 * 4] = m;
        ushort4 mh, ml;
        mh.x = f2b(m.x); ml.x = f2b(m.x - b2f(mh.x));
        mh.y = f2b(m.y); ml.y = f2b(m.y - b2f(mh.y));
        mh.z = f2b(m.z); ml.z = f2b(m.z - b2f(mh.z));
        mh.w = f2b(m.w); ml.w = f2b(m.w - b2f(mh.w));
        *(ushort4*)&s2h[(row0 + g) * 128 + c4 * 4] = mh;
        *(ushort4*)&s2l[(row0 + g) * 128 + c4 * 4] = ml;
    }
    __syncthreads();

    // G3 gathers prefetched (consumed in combine3, hidden behind base3 MFMA)
    float4 g3r[2][KNN];
    {
        int c4 = tid & 63, g = tid >> 6;
        if (!FIRST) {
#pragma unroll
            for (int r = 0; r < 2; ++r)
#pragma unroll
                for (int k = 0; k < KNN; ++k)
                    g3r[r][k] = ((const float4*)G3p)[(bN + jss[2][2 * g + r][k]) * 64 + c4];
        }
    }

    // P4: base3 = s2 @ W3f + b3 on MFMA -> s3b (2 column tiles per wave)
    {
        int col0 = wv * 16 + fm, col1 = (wv + 8) * 16 + fm;
        float bz0 = b3[col0], bz1 = b3[col1];
        f4_t a0 = {bz0, bz0, bz0, bz0};
        f4_t a1 = {bz1, bz1, bz1, bz1};
#pragma unroll
        for (int k0 = 0; k0 < 128; k0 += 32) {
            bf8_t ah, al; cvt8(&s2s[fm][k0 + quad * 8], ah, al);
            bf8_t b0h = *(const bf8_t*)(w3fh + col0 * 128 + k0 + quad * 8);
            bf8_t b0l = *(const bf8_t*)(w3fl + col0 * 128 + k0 + quad * 8);
            bf8_t b1h = *(const bf8_t*)(w3fh + col1 * 128 + k0 + quad * 8);
            bf8_t b1l = *(const bf8_t*)(w3fl + col1 * 128 + k0 + quad * 8);
            a0 = __builtin_amdgcn_mfma_f32_16x16x32_bf16(ah, b0h, a0, 0, 0, 0);
            a0 = __builtin_amdgcn_mfma_f32_16x16x32_bf16(ah, b0l, a0, 0, 0, 0);
            a0 = __builtin_amdgcn_mfma_f32_16x16x32_bf16(al, b0h, a0, 0, 0, 0);
            a1 = __builtin_amdgcn_mfma_f32_16x16x32_bf16(ah, b1h, a1, 0, 0, 0);
            a1 = __builtin_amdgcn_mfma_f32_16x16x32_bf16(ah, b1l, a1, 0, 0, 0);
            a1 = __builtin_amdgcn_mfma_f32_16x16x32_bf16(al, b1h, a1, 0, 0, 0);
        }
#pragma unroll
        for (int r = 0; r < 4; ++r) {
            s3b[quad * 4 + r][col0] = a0[r];
            s3b[quad * 4 + r][col1] = a1[r];
        }
    }
    __syncthreads();

    // P5: combine3 in place on s3b + split-bf16 global store
    {
        int c4 = tid & 63, g = tid >> 6;
        float4 wx = ((const float4*)W3)[c4];
        float4 wy = ((const float4*)(W3 + 256))[c4];
        float4 wz = ((const float4*)(W3 + 512))[c4];
#pragma unroll
        for (int r = 0; r < 2; ++r) {
            int p = 2 * g + r;
            float4 bse = *(float4*)&s3b[p][c4 * 4];
            float4 m = make_float4(-1e30f, -1e30f, -1e30f, -1e30f);
#pragma unroll
            for (int k = 0; k < KNN; ++k) {
                float dx = dsp[2][p][k][0], dy = dsp[2][p][k][1], dz = dsp[2][p][k][2];
                float4 v;
                v.x = fmaf(dz, wz.x, fmaf(dy, wy.x, fmaf(dx, wx.x, bse.x)));
                v.y = fmaf(dz, wz.y, fmaf(dy, wy.y, fmaf(dx, wx.y, bse.y)));
                v.z = fmaf(dz, wz.z, fmaf(dy, wy.z, fmaf(dx, wx.z, bse.z)));
                v.w = fmaf(dz, wz.w, fmaf(dy, wy.w, fmaf(dx, wx.w, bse.w)));
                if (!FIRST) {
                    v.x += g3r[r][k].x; v.y += g3r[r][k].y;
                    v.z += g3r[r][k].z; v.w += g3r[r][k].w;
                }
                m.x = fmaxf(m.x, v.x); m.y = fmaxf(m.y, v.y);
                m.z = fmaxf(m.z, v.z); m.w = fmaxf(m.w, v.w);
            }
            *(float4*)&s3b[p][c4 * 4] = m;
            ushort4 mh, ml;
            mh.x = f2b(m.x); ml.x = f2b(m.x - b2f(mh.x));
            mh.y = f2b(m.y); ml.y = f2b(m.y - b2f(mh.y));
            mh.z = f2b(m.z); ml.z = f2b(m.z - b2f(mh.z));
            mh.w = f2b(m.w); ml.w = f2b(m.w - b2f(mh.w));
            *(ushort4*)&s3h[(row0 + p) * 256 + c4 * 4] = mh;
            *(ushort4*)&s3l[(row0 + p) * 256 + c4 * 4] = ml;
        }
    }

    // P6: prediction head — h = relu(s3 @ Wm + bm) on MFMA, then motion
    if (do_head) {
        __syncthreads();
        if (wv < 4) {
            int col = wv * 16 + fm;
            float bz = bm[col];
            f4_t acc = {bz, bz, bz, bz};
#pragma unroll
            for (int k0 = 0; k0 < 256; k0 += 32) {
                bf8_t ah, al; cvt8(&s3b[fm][k0 + quad * 8], ah, al);
                bf8_t bh = *(const bf8_t*)(wmh + col * 256 + k0 + quad * 8);
                bf8_t bl = *(const bf8_t*)(wml + col * 256 + k0 + quad * 8);
                acc = __builtin_amdgcn_mfma_f32_16x16x32_bf16(ah, bh, acc, 0, 0, 0);
                acc = __builtin_amdgcn_mfma_f32_16x16x32_bf16(ah, bl, acc, 0, 0, 0);
                acc = __builtin_amdgcn_mfma_f32_16x16x32_bf16(al, bh, acc, 0, 0, 0);
            }
#pragma unroll
            for (int r = 0; r < 4; ++r)
                hs[quad * 4 + r][col] = fmaxf(acc[r], 0.f);
        }
        __syncthreads();
        if (tid < PB * 3) {
            int p = tid / 3, d = tid % 3;
            float m = bl[d];
#pragma unroll 4
            for (int c = 0; c < 64; ++c)
                m = fmaf(hs[p][c], Wl[c * 3 + d], m);
            const float* qp = xq + (long)b * xq_bs + (n0 + p) * 3;
            xnext[(long)b * xn_bs + (n0 + p) * 3 + d] = qp[d] + m;
        }
    }
}

// ---------------------------------------------------------------------------
// Kernel B: tiled MFMA GEMM (unchanged tile), batch<->XCD swizzle so the G/s
// rows of batch b are produced on XCD b/2 (same as cells' consumers).
// ---------------------------------------------------------------------------
template<int N>
__device__ __forceinline__ void gemmTile(
        const ushort* __restrict__ Ah, const ushort* __restrict__ Al,
        const ushort* __restrict__ Bh, const ushort* __restrict__ Bl,
        float* __restrict__ G, int rb, int cb, int tid, ushort* lds) {
    const int row0 = rb * 128, c0 = cb * 64;
    ushort* ah = lds;
    ushort* al = lds + 128 * 40;
    ushort* bh = lds + 256 * 40;
    ushort* bl = lds + 320 * 40;
    const int wv = tid >> 6, lane = tid & 63;
    const int m = lane & 15, quad = lane >> 4;
    const int wm0 = wv * 32;
    const int lr = tid >> 2, ls = (tid & 3) * 8;

    f4_t acc[2][4];
#pragma unroll
    for (int rt = 0; rt < 2; ++rt)
#pragma unroll
        for (int ct = 0; ct < 4; ++ct) acc[rt][ct] = (f4_t){0.f, 0.f, 0.f, 0.f};

    bf8_t pah0, pah1, pal0, pal1, pbh, pbl;
    pah0 = *(const bf8_t*)(Ah + (long)(row0 + lr) * N + ls);
    pah1 = *(const bf8_t*)(Ah + (long)(row0 + 64 + lr) * N + ls);
    pal0 = *(const bf8_t*)(Al + (long)(row0 + lr) * N + ls);
    pal1 = *(const bf8_t*)(Al + (long)(row0 + 64 + lr) * N + ls);
    pbh  = *(const bf8_t*)(Bh + (long)(c0 + lr) * N + ls);
    pbl  = *(const bf8_t*)(Bl + (long)(c0 + lr) * N + ls);

    for (int k0 = 0; k0 < N; k0 += 32) {
        if (k0) __syncthreads();
        *(bf8_t*)(ah + lr * 40 + ls) = pah0;
        *(bf8_t*)(ah + (64 + lr) * 40 + ls) = pah1;
        *(bf8_t*)(al + lr * 40 + ls) = pal0;
        *(bf8_t*)(al + (64 + lr) * 40 + ls) = pal1;
        *(bf8_t*)(bh + lr * 40 + ls) = pbh;
        *(bf8_t*)(bl + lr * 40 + ls) = pbl;
        __syncthreads();
        if (k0 + 32 < N) {
            int kn = k0 + 32;
            pah0 = *(const bf8_t*)(Ah + (long)(row0 + lr) * N + kn + ls);
            pah1 = *(const bf8_t*)(Ah + (long)(row0 + 64 + lr) * N + kn + ls);
            pal0 = *(const bf8_t*)(Al + (long)(row0 + lr) * N + kn + ls);
            pal1 = *(const bf8_t*)(Al + (long)(row0 + 64 + lr) * N + kn + ls);
            pbh  = *(const bf8_t*)(Bh + (long)(c0 + lr) * N + kn + ls);
            pbl  = *(const bf8_t*)(Bl + (long)(c0 + lr) * N + kn + ls);
        }
        bf8_t a0h = *(const bf8_t*)(ah + (wm0 + m) * 40 + quad * 8);
        bf8_t a0l = *(const bf8_t*)(al + (wm0 + m) * 40 + quad * 8);
        bf8_t a1h = *(const bf8_t*)(ah + (wm0 + 16 + m) * 40 + quad * 8);
        bf8_t a1l = *(const bf8_t*)(al + (wm0 + 16 + m) * 40 + quad * 8);
#pragma unroll
        for (int ct = 0; ct < 4; ++ct) {
            bf8_t bth = *(const bf8_t*)(bh + (ct * 16 + m) * 40 + quad * 8);
            bf8_t btl = *(const bf8_t*)(bl + (ct * 16 + m) * 40 + quad * 8);
            acc[0][ct] = __builtin_amdgcn_mfma_f32_16x16x32_bf16(a0h, bth, acc[0][ct], 0, 0, 0);
            acc[0][ct] = __builtin_amdgcn_mfma_f32_16x16x32_bf16(a0h, btl, acc[0][ct], 0, 0, 0);
            acc[0][ct] = __builtin_amdgcn_mfma_f32_16x16x32_bf16(a0l, bth, acc[0][ct], 0, 0, 0);
            acc[1][ct] = __builtin_amdgcn_mfma_f32_16x16x32_bf16(a1h, bth, acc[1][ct], 0, 0, 0);
            acc[1][ct] = __builtin_amdgcn_mfma_f32_16x16x32_bf16(a1h, btl, acc[1][ct], 0, 0, 0);
            acc[1][ct] = __builtin_amdgcn_mfma_f32_16x16x32_bf16(a1l, bth, acc[1][ct], 0, 0, 0);
        }
    }
#pragma unroll
    for (int rt = 0; rt < 2; ++rt)
#pragma unroll
        for (int ct = 0; ct < 4; ++ct) {
            int col = c0 + ct * 16 + m;
#pragma unroll
            for (int r = 0; r < 4; ++r)
                G[(long)(row0 + wm0 + rt * 16 + quad * 4 + r) * N + col] = acc[rt][ct][r];
        }
}

__global__ __launch_bounds__(256) void gemmG_kernel(
        const ushort* __restrict__ s1h, const ushort* __restrict__ s1l,
        const ushort* __restrict__ s2h, const ushort* __restrict__ s2l,
        const ushort* __restrict__ s3h, const ushort* __restrict__ s3l,
        const ushort* __restrict__ w1h, const ushort* __restrict__ w1l,
        const ushort* __restrict__ w2h, const ushort* __restrict__ w2l,
        const ushort* __restrict__ w3h, const ushort* __restrict__ w3l,
        float* __restrict__ G1, float* __restrict__ G2,
        float* __restrict__ G3) {
    __shared__ ushort lds[384 * 40];
    int bx = blockIdx.x, tid = threadIdx.x;
    if (bx < 256) {
        int xcd = bx & 7, rem = bx >> 3;           // rb/8 == xcd
        int rb = xcd * 8 + (rem & 7), cb = rem >> 3;
        gemmTile<256>(s3h, s3l, w3h, w3l, G3, rb, cb, tid, lds);
    } else if (bx < 384) {
        int u = bx - 256; int xcd = u & 7, rem = u >> 3;
        int rb = xcd * 8 + (rem & 7), cb = rem >> 3;
        gemmTile<128>(s2h, s2l, w2h, w2l, G2, rb, cb, tid, lds);
    } else {
        int u = bx - 384; int xcd = u & 7, j = u >> 3;
        gemmTile<64>(s1h, s1l, w1h, w1l, G1, xcd * 8 + j, 0, tid, lds);
    }
}

extern "C" void kernel_launch(void* const* d_in, const int* in_sizes, int n_in,
                              void* d_out, int out_size, void* d_ws, size_t ws_size,
                              hipStream_t stream) {
    const float* frames = (const float*)d_in[0];
    const float* W1 = (const float*)d_in[1]; const float* b1 = (const float*)d_in[2];
    const float* W2 = (const float*)d_in[3]; const float* b2 = (const float*)d_in[4];
    const float* W3 = (const float*)d_in[5]; const float* b3 = (const float*)d_in[6];
    const float* Wm = (const float*)d_in[7]; const float* bm = (const float*)d_in[8];
    const float* Wl = (const float*)d_in[9]; const float* bl = (const float*)d_in[10];
    float* out = (float*)d_out;

    const long M = (long)BB * NN;    // 8192
    float* ws = (float*)d_ws;
    float* G1b = ws; ws += M * 64;
    float* G2b = ws; ws += M * 128;
    float* G3b = ws; ws += M * 256;
    ushort* us = (ushort*)ws;
    ushort* s1h = us; us += M * 64;   ushort* s1l = us; us += M * 64;
    ushort* s2h = us; us += M * 128;  ushort* s2l = us; us += M * 128;
    ushort* s3h = us; us += M * 256;  ushort* s3l = us; us += M * 256;
    ushort* w1h = us; us += 4096;     ushort* w1l = us; us += 4096;
    ushort* w2h = us; us += 16384;    ushort* w2l = us; us += 16384;
    ushort* w3h = us; us += 65536;    ushort* w3l = us; us += 65536;
    ushort* w2fh = us; us += 8192;    ushort* w2fl = us; us += 8192;
    ushort* w3fh = us; us += 32768;   ushort* w3fl = us; us += 32768;
    ushort* wmh = us; us += 16384;    ushort* wml = us; us += 16384;
    const long BNK = M * KNN;
    int* ip = (int*)us;
    int* idx1w = ip; ip += 7 * BNK;
    int* idx2w = ip; ip += 7 * BNK;
    int* idx3w = ip; ip += 7 * BNK;

    double ra = 4.0 + 1e-6, rb = 8.0 + 1e-6, rc = 12.0 + 1e-6;
    float r2a = (float)(ra * ra), r2b = (float)(rb * rb), r2c = (float)(rc * rc);

    const int FB = SEQ * NN * 3;
    const int OB = 6 * NN * 3;

    convW_kernel<<<560, 256, 0, stream>>>(W1, W2, W3, Wm,
                                          w1h, w1l, w2h, w2l, w3h, w3l,
                                          w2fh, w2fl, w3fh, w3fl, wmh, wml);
    knn_kernel<<<dim3(NN / QB, BB, 7), 256, 0, stream>>>(
        frames, FB, nullptr, 0, idx1w, idx2w, idx3w, r2a, r2b, r2c, 1);

    for (int t = 0; t < SEQ; ++t) {
        const float* xq; int xq_bs;
        const float* xs; int xs_bs;
        if (t < 6)       { xq = frames + (long)t * NN * 3;        xq_bs = FB; }
        else if (t == 6) { xq = frames + 5L * NN * 3;             xq_bs = FB; }
        else             { xq = out + (long)(t - 7) * NN * 3;     xq_bs = OB; }
        if (t == 0)      { xs = xq;                               xs_bs = xq_bs; }
        else if (t <= 6) { xs = frames + (long)(t - 1) * NN * 3;  xs_bs = FB; }
        else if (t == 7) { xs = frames + 5L * NN * 3;             xs_bs = FB; }
        else             { xs = out + (long)(t - 8) * NN * 3;     xs_bs = OB; }

        int slot = (t <= 6) ? t : 0;
        int* i1 = idx1w + slot * BNK;
        int* i2 = idx2w + slot * BNK;
        int* i3 = idx3w + slot * BNK;

        if (t >= 7)
            knn_kernel<<<dim3(NN / QB, BB, 1), 256, 0, stream>>>(
                xq, xq_bs, xs, xs_bs, i1, i2, i3, r2a, r2b, r2c, 0);

        int do_head = (t >= 6);
        float* xnext = do_head ? out + (long)(t - 6) * NN * 3 : nullptr;

        if (t == 0)
            cells_kernel<true><<<BB * NN / PB, 512, 0, stream>>>(
                xq, xq_bs, xs, xs_bs, i1, i2, i3,
                G1b, G2b, G3b, s1h, s1l, s2h, s2l, s3h, s3l,
                W1, b1, W2, b2, W3, b3,
                w2fh, w2fl, w3fh, w3fl, wmh, wml, bm,
                Wl, bl, xnext, OB, do_head);
        else
            cells_kernel<false><<<BB * NN / PB, 512, 0, stream>>>(
                xq, xq_bs, xs, xs_bs, i1, i2, i3,
                G1b, G2b, G3b, s1h, s1l, s2h, s2l, s3h, s3l,
                W1, b1, W2, b2, W3, b3,
                w2fh, w2fl, w3fh, w3fl, wmh, wml, bm,
                Wl, bl, xnext, OB, do_head);

        if (t < SEQ - 1)
            gemmG_kernel<<<448, 256, 0, stream>>>(
                s1h, s1l, s2h, s2l, s3h, s3l,
                w1h, w1l, w2h, w2l, w3h, w3l,
                G1b, G2b, G3b);
    }
}